// Round 1
// baseline (208.615 us; speedup 1.0000x reference)
//
#include <hip/hip_runtime.h>
#include <stdint.h>

// Causal SDPA B=4,H=16,S=2048,D=64 fp32. Flash-MFMA bf16, round 5.
// convert_prep: UNCHANGED (control for the total-vs-kernel gap).
// sdpa_mfma v5: 32x32x16 MFMA + fully in-register softmax (T12):
//   S^T = K.Q^T -> lane holds P for its own q row; P->A-frag via
//   4x v_cvt_pk_bf16_f32 + 2x v_permlane32_swap_b32 per 16-k fragment.
//   P LDS buffer deleted (-18.4KB LDS, -12 LDS ops/wave-tile).
//   Double-buffered K/V LDS, ONE barrier per k-tile; prefetch issued
//   after the barrier so the vmcnt(0) barrier-drain doesn't serialize it.
//   setprio(1) around MFMA clusters (T5). Balanced (A,31-A) pairing kept.

#define SLEN 2048
#define DHEAD 64
#define NHEADS 64
#define NELEM (SLEN * DHEAD * NHEADS)   // 8388608 per tensor

typedef short bf16x8 __attribute__((ext_vector_type(8)));
typedef float f32x16 __attribute__((ext_vector_type(16)));

__device__ __forceinline__ uint32_t pkbf(float hi, float lo) {
    uint32_t a = __builtin_bit_cast(uint32_t, lo) + 0x8000u;
    uint32_t b = __builtin_bit_cast(uint32_t, hi) + 0x8000u;
    return __builtin_amdgcn_perm(b, a, 0x07060302u);
}
__device__ __forceinline__ unsigned short f2bf(float f) {
    return (unsigned short)((__builtin_bit_cast(uint32_t, f) + 0x8000u) >> 16);
}
__device__ __forceinline__ int swz(int row, int g) {  // offset in shorts, 64x64 tile
    return row * 64 + ((g ^ (row & 7)) << 3);
}

// ---------------- pass 1: K straight, V transposed (identical to prior rounds) ----------------
__global__ __launch_bounds__(256)
void convert_prep(const float* __restrict__ K, const float* __restrict__ V,
                  unsigned short* __restrict__ Kb, unsigned short* __restrict__ Vtb) {
    __shared__ unsigned short Lt[64 * 264];
    const int b = blockIdx.x, t = threadIdx.x;
    if (b < 4096) {
        const int off = (b * 256 + t) * 8;
        float4 a = *(const float4*)(K + off);
        float4 c = *(const float4*)(K + off + 4);
        uint4 o;
        o.x = pkbf(a.y, a.x); o.y = pkbf(a.w, a.z);
        o.z = pkbf(c.y, c.x); o.w = pkbf(c.w, c.z);
        *(uint4*)(Kb + off) = o;
    } else {
        const int vb2 = b - 4096;
        const int head = vb2 >> 3, kblk = vb2 & 7;
        const float* Vh = V + (size_t)head * (SLEN * DHEAD) + kblk * 256 * DHEAD;
        unsigned short* Vo = Vtb + (size_t)head * (SLEN * DHEAD) + kblk * 256;
#pragma unroll
        for (int i = 0; i < 16; ++i) {
            int idx = t + 256 * i;
            int key = idx >> 4, d4 = idx & 15;
            float4 v = *(const float4*)(Vh + key * DHEAD + d4 * 4);
            Lt[(d4 * 4 + 0) * 264 + key] = f2bf(v.x);
            Lt[(d4 * 4 + 1) * 264 + key] = f2bf(v.y);
            Lt[(d4 * 4 + 2) * 264 + key] = f2bf(v.z);
            Lt[(d4 * 4 + 3) * 264 + key] = f2bf(v.w);
        }
        __syncthreads();
#pragma unroll
        for (int jj = 0; jj < 8; ++jj) {
            int idx = t + 256 * jj;
            int d = idx >> 5, k8 = idx & 31;
            *(uint4*)(Vo + (size_t)d * SLEN + k8 * 8) = *(const uint4*)(Lt + d * 264 + k8 * 8);
        }
    }
}

// ---------------- pass 2: flash attention, 32x32 MFMA + register softmax ----------------
__global__ __launch_bounds__(256, 4)
void sdpa_mfma(const float* __restrict__ Qf, const unsigned short* __restrict__ Kb,
               const unsigned short* __restrict__ Vtb, float* __restrict__ Og) {
    const int n = blockIdx.x;
    const int j = n >> 8, c = n & 255;
    const int head = c & 63;
    const int A  = (c >> 6) + 4 * j;   // 0..15
    const int Bq = 31 - A;             // 16..31

    const size_t hb = (size_t)head * SLEN * DHEAD;
    const float* Qh = Qf + hb;
    const unsigned short* Kh  = Kb + hb;
    const unsigned short* Vth = Vtb + hb;   // [d][2048]
    float* Oh = Og + hb;

    const int tid  = threadIdx.x;
    const int w    = tid >> 6, lane = tid & 63;
    const int q32  = lane & 31, hi = lane >> 5;

    __shared__ __align__(16) unsigned short Kl[2][64 * 64];  // 16 KB, swizzled [key][d]
    __shared__ __align__(16) unsigned short Vl[2][64 * 64];  // 16 KB, swizzled [d][key]

    // waves 0,1 -> tile A; waves 2,3 -> tile B (balanced pairing, 33 units/block)
    const int qw = ((w < 2) ? A * 64 : Bq * 64) + (w & 1) * 32;

    // Q B-frags from fp32 global (once per block): lane holds Q[qw+q32][dc*16+hi*8 .. +7]
    bf16x8 qf[4];
#pragma unroll
    for (int dc = 0; dc < 4; ++dc) {
        const float* src = Qh + (size_t)(qw + q32) * DHEAD + dc * 16 + hi * 8;
        float4 a = *(const float4*)src;
        float4 b = *(const float4*)(src + 4);
        uint4 u;
        u.x = pkbf(a.y, a.x); u.y = pkbf(a.w, a.z);
        u.z = pkbf(b.y, b.x); u.w = pkbf(b.w, b.z);
        qf[dc] = __builtin_bit_cast(bf16x8, u);
    }

    f32x16 o0 = (f32x16)(0.0f);   // d = q32      (cols 0..31)
    f32x16 o1 = (f32x16)(0.0f);   // d = 32 + q32 (cols 32..63)
    float ls = 0.f;
    const float SCL = 0.18033688f;   // (1/8) * log2(e)

    // staging: 256 threads x 2 uint4 per tensor (tile = 512 uint4)
    const int p1 = tid + 256;
    const int srow0 = tid >> 3, sg0 = tid & 7;
    const int srow1 = p1 >> 3,  sg1 = p1 & 7;
    const int lo0 = swz(srow0, sg0), lo1 = swz(srow1, sg1);
    const size_t kS0 = (size_t)srow0 * DHEAD + sg0 * 8, kS1 = (size_t)srow1 * DHEAD + sg1 * 8;
    const size_t vS0 = (size_t)srow0 * SLEN + sg0 * 8,  vS1 = (size_t)srow1 * SLEN + sg1 * 8;

    const int ntiles = Bq + 1;
    uint4 kr0 = *(const uint4*)(Kh + kS0), kr1 = *(const uint4*)(Kh + kS1);
    uint4 vr0 = *(const uint4*)(Vth + vS0), vr1 = *(const uint4*)(Vth + vS1);

    for (int t = 0; t < ntiles; ++t) {
        const int k0 = t * 64;
        unsigned short* Kc = Kl[t & 1];
        unsigned short* Vc = Vl[t & 1];
        // write tile t (safe: previous readers of this buffer finished before barrier t-1)
        *(uint4*)(Kc + lo0) = kr0; *(uint4*)(Kc + lo1) = kr1;
        *(uint4*)(Vc + lo0) = vr0; *(uint4*)(Vc + lo1) = vr1;
        __syncthreads();
        // prefetch AFTER the barrier so the vmcnt(0) barrier-drain doesn't serialize it;
        // loads overlap the compute phase below, consumed at next iteration's writes.
        if (t + 1 < ntiles) {
            const size_t ko = (size_t)(k0 + 64) * DHEAD;
            kr0 = *(const uint4*)(Kh + kS0 + ko);
            kr1 = *(const uint4*)(Kh + kS1 + ko);
            vr0 = *(const uint4*)(Vth + vS0 + (k0 + 64));
            vr1 = *(const uint4*)(Vth + vS1 + (k0 + 64));
        }
        if (k0 <= qw + 31) {
            const bool partial = (k0 + 63 > qw);
            const int qrel = qw + q32 - k0 - 4 * hi;   // key-budget for this lane (kc=0)
#pragma unroll
            for (int kc = 0; kc < 2; ++kc) {
                // S^T chunk (32 keys x 32 q): A = K rows kc*32+l&31, B = Q^T
                f32x16 s = (f32x16)(0.0f);
                __builtin_amdgcn_s_setprio(1);
#pragma unroll
                for (int dc = 0; dc < 4; ++dc) {
                    bf16x8 kf = __builtin_bit_cast(bf16x8,
                        *(const uint4*)(Kc + swz(kc * 32 + q32, 2 * dc + hi)));
                    s = __builtin_amdgcn_mfma_f32_32x32x16_bf16(kf, qf[dc], s, 0, 0, 0);
                }
                __builtin_amdgcn_s_setprio(0);
                // exp2 + causal mask; lane's P row is its own q -> no cross-lane reduce
                float p[16];
                const int qr = qrel - kc * 32;
#pragma unroll
                for (int r = 0; r < 16; ++r) {
                    float e = __builtin_amdgcn_exp2f(s[r] * SCL);
                    if (partial) {
                        const int crow = (r & 3) + 8 * (r >> 2);
                        e = (crow <= qr) ? e : 0.f;
                    }
                    p[r] = e;
                }
                ls += ((p[0] + p[1]) + (p[2] + p[3])) + ((p[4] + p[5]) + (p[6] + p[7]))
                    + ((p[8] + p[9]) + (p[10] + p[11])) + ((p[12] + p[13]) + (p[14] + p[15]));
                // P -> PV A-frags, fully in-register (m214 T12 recipe):
                // word(k0,k1)=cvt_pk(p0,p1) ... swap with word(k8,k9) across lane+-32.
                bf16x8 pf[2];
#pragma unroll
                for (int sub = 0; sub < 2; ++sub) {
                    uint32_t w0, w1, w2, w3;
                    asm("v_cvt_pk_bf16_f32 %0, %1, %2" : "=v"(w0) : "v"(p[8*sub+0]), "v"(p[8*sub+1]));
                    asm("v_cvt_pk_bf16_f32 %0, %1, %2" : "=v"(w1) : "v"(p[8*sub+2]), "v"(p[8*sub+3]));
                    asm("v_cvt_pk_bf16_f32 %0, %1, %2" : "=v"(w2) : "v"(p[8*sub+4]), "v"(p[8*sub+5]));
                    asm("v_cvt_pk_bf16_f32 %0, %1, %2" : "=v"(w3) : "v"(p[8*sub+6]), "v"(p[8*sub+7]));
                    asm("v_permlane32_swap_b32 %0, %1" : "+v"(w0), "+v"(w2));
                    asm("v_permlane32_swap_b32 %0, %1" : "+v"(w1), "+v"(w3));
                    uint4 u; u.x = w0; u.y = w1; u.z = w2; u.w = w3;
                    pf[sub] = __builtin_bit_cast(bf16x8, u);
                }
                // O += P.V for this 32-k chunk; B = V (k x d) from V^T LDS
                __builtin_amdgcn_s_setprio(1);
#pragma unroll
                for (int sub = 0; sub < 2; ++sub) {
                    const int ks = kc * 2 + sub;
                    bf16x8 vf0 = __builtin_bit_cast(bf16x8,
                        *(const uint4*)(Vc + swz(q32,      2 * ks + hi)));
                    bf16x8 vf1 = __builtin_bit_cast(bf16x8,
                        *(const uint4*)(Vc + swz(32 + q32, 2 * ks + hi)));
                    o0 = __builtin_amdgcn_mfma_f32_32x32x16_bf16(pf[sub], vf0, o0, 0, 0, 0);
                    o1 = __builtin_amdgcn_mfma_f32_32x32x16_bf16(pf[sub], vf1, o1, 0, 0, 0);
                }
                __builtin_amdgcn_s_setprio(0);
            }
        }
    }

    // denominator: lane's ls covers its q for its hi-half rows; fold halves
    float lst = ls + __shfl_xor(ls, 32);

    // O layout: col d = (dc2*32 + q32), row q = qw + crow(r,hi); normalize + store
#pragma unroll
    for (int r = 0; r < 16; ++r) {
        const int crow = (r & 3) + 8 * (r >> 2) + 4 * hi;
        const float inv = 1.0f / __shfl(lst, crow);
        float* dst = Oh + (size_t)(qw + crow) * DHEAD + q32;
        dst[0]  = o0[r] * inv;
        dst[32] = o1[r] * inv;
    }
}

extern "C" void kernel_launch(void* const* d_in, const int* in_sizes, int n_in,
                              void* d_out, int out_size, void* d_ws, size_t ws_size,
                              hipStream_t stream) {
    const float* Q = (const float*)d_in[0];
    const float* K = (const float*)d_in[1];
    const float* V = (const float*)d_in[2];
    float*       O = (float*)d_out;

    unsigned short* Kbf  = (unsigned short*)d_ws;
    unsigned short* Vtbf = Kbf + NELEM;

    convert_prep<<<dim3(4096 + 512), dim3(256), 0, stream>>>(K, V, Kbf, Vtbf);
    sdpa_mfma<<<dim3(1024), dim3(256), 0, stream>>>(Q, Kbf, Vtbf, O);
}